// Round 1
// baseline (8000.140 us; speedup 1.0000x reference)
//
#include <hip/hip_runtime.h>
#include <cstdint>
#include <cstddef>

#define B_  64
#define T_  512
#define S_  512
#define D_  256
#define G4  1024  // 4*D

// ---- workspace layout (in floats) ----
// Wc      [0,        262144)   : W_ih + W_hh, row-major [4D][D]
// bias    [262144,   263168)   : b_ih + b_hh
// hbuf0   [263168,  +16384)    : h state ping  ([k][b] layout, 256x64)
// hbuf1   (+16384)             : h state pong
// ebuf    (+16384)             : e0 transposed [k][b]
// cbuf    (+16384)             : c state [d][b]
static const size_t WS_WC   = 0;
static const size_t WS_BIAS = 262144;
static const size_t WS_H0   = 263168;
static const size_t WS_H1   = WS_H0 + 16384;
static const size_t WS_E    = WS_H1 + 16384;
static const size_t WS_C    = WS_E  + 16384;

// -------------------- prep kernels --------------------

__global__ __launch_bounds__(256) void prep_weights(
    const float* __restrict__ Wih, const float* __restrict__ Whh,
    const float* __restrict__ bih, const float* __restrict__ bhh,
    float* __restrict__ ws)
{
    int i = blockIdx.x * 256 + threadIdx.x;
    if (i < G4 * D_) {
        ws[WS_WC + i] = Wih[i] + Whh[i];
    } else if (i < G4 * D_ + G4) {
        int j = i - G4 * D_;
        ws[WS_BIAS + j] = bih[j] + bhh[j];
    }
}

__global__ __launch_bounds__(256) void prep_state(
    const float* __restrict__ h0, const float* __restrict__ c0,
    const float* __restrict__ de, float* __restrict__ ws)
{
    int i = blockIdx.x * 256 + threadIdx.x;  // i = k*64 + b, 16384 total
    int k = i >> 6, b = i & 63;
    ws[WS_H0 + i] = h0[b * D_ + k];                 // h0 transposed [k][b]
    ws[WS_C  + i] = c0[b * D_ + k];                 // c state [d][b]
    ws[WS_E  + i] = de[(size_t)b * T_ * D_ + k];    // e0 = embeds[:,0,:] transposed
}

// -------------------- LSTM step --------------------

__device__ __forceinline__ void dot4_acc(
    const float* __restrict__ W, int d, const float* __restrict__ hl, int b,
    float& ai, float& af, float& ag, float& ao)
{
    const float4* wi = (const float4*)(W + (size_t)d * D_);
    const float4* wf = (const float4*)(W + (size_t)(D_   + d) * D_);
    const float4* wg = (const float4*)(W + (size_t)(2*D_ + d) * D_);
    const float4* wo = (const float4*)(W + (size_t)(3*D_ + d) * D_);
    #pragma unroll 4
    for (int k4 = 0; k4 < 64; ++k4) {
        float4 vi = wi[k4], vf = wf[k4], vg = wg[k4], vo = wo[k4];
        float h0v = hl[(4*k4 + 0) * 64 + b];
        float h1v = hl[(4*k4 + 1) * 64 + b];
        float h2v = hl[(4*k4 + 2) * 64 + b];
        float h3v = hl[(4*k4 + 3) * 64 + b];
        ai += vi.x*h0v + vi.y*h1v + vi.z*h2v + vi.w*h3v;
        af += vf.x*h0v + vf.y*h1v + vf.z*h2v + vf.w*h3v;
        ag += vg.x*h0v + vg.y*h1v + vg.z*h2v + vg.w*h3v;
        ao += vo.x*h0v + vo.y*h1v + vo.z*h2v + vo.w*h3v;
    }
}

__device__ __forceinline__ void stage16k(float* __restrict__ hl,
                                         const float* __restrict__ src, int tid)
{
    const float4* s4 = (const float4*)src;
    float4* d4 = (float4*)hl;
    #pragma unroll
    for (int m = 0; m < 16; ++m) d4[m * 256 + tid] = s4[m * 256 + tid];
}

__global__ __launch_bounds__(256) void lstm_step(
    const float* __restrict__ Wc, const float* __restrict__ bias,
    const float* __restrict__ Wih, const float* __restrict__ Whh,
    const float* __restrict__ hprev, float* __restrict__ hnext,
    const float* __restrict__ ebuf, float* __restrict__ cbuf,
    float* __restrict__ out, int t)
{
    __shared__ float hl[D_ * 64];  // 64 KiB, [k][b]
    int tid = threadIdx.x;
    int b   = tid & 63;
    int dl  = tid >> 6;
    int d   = blockIdx.x * 4 + dl;

    float ai = bias[d];
    float af = bias[D_   + d];
    float ag = bias[2*D_ + d];
    float ao = bias[3*D_ + d];

    stage16k(hl, hprev, tid);
    __syncthreads();

    if (t == 0) {
        // gates0 = e0 @ W_ih^T + h0 @ W_hh^T + bias
        dot4_acc(Whh, d, hl, b, ai, af, ag, ao);
        __syncthreads();
        stage16k(hl, ebuf, tid);
        __syncthreads();
        dot4_acc(Wih, d, hl, b, ai, af, ag, ao);
    } else {
        dot4_acc(Wc, d, hl, b, ai, af, ag, ao);
    }

    float c  = cbuf[d * 64 + b];
    float si = 1.0f / (1.0f + expf(-ai));
    float sf = 1.0f / (1.0f + expf(-af));
    float so = 1.0f / (1.0f + expf(-ao));
    float tg = tanhf(ag);
    float cn = sf * c + si * tg;
    float hn = so * tanhf(cn);

    cbuf[d * 64 + b]  = cn;
    hnext[d * 64 + b] = hn;
    out[((size_t)b * T_ + t) * (2 * D_) + d] = hn;
}

// -------------------- attention --------------------
// One block per (b, 16-row t-tile). H is read back from out[..., 0:256].

__global__ __launch_bounds__(256) void attn_kernel(
    const float* __restrict__ E, float* __restrict__ out)
{
    int tt = blockIdx.x;   // 0..31
    int b  = blockIdx.y;   // 0..63
    int t0 = tt * 16;
    int tid = threadIdx.x;

    __shared__ float Ht[16 * 260];   // padded stride 260
    __shared__ float sc[16 * 520];   // scores, padded stride 520
    __shared__ float rsum[16];

    // stage H tile from out[b][t0+t][0:256]
    #pragma unroll
    for (int m = 0; m < 4; ++m) {
        int f = m * 256 + tid;       // float4 index over 1024
        int t = f >> 6, j = f & 63;
        float4 v = *(const float4*)(out + ((size_t)b * T_ + t0 + t) * 512 + 4 * j);
        *(float4*)(Ht + t * 260 + 4 * j) = v;
    }
    __syncthreads();

    const float4* E4 = (const float4*)E + (size_t)b * S_ * 64;

    // ---- phase A: scores[t][s] = H[t] . E[s] ----
    int r  = tid >> 5;   // 0..7   -> rows r and r+8
    int cc = tid & 31;   // 0..31  -> cols cc + 32*j
    float accA[16], accB[16];
    #pragma unroll
    for (int jj = 0; jj < 16; ++jj) { accA[jj] = 0.f; accB[jj] = 0.f; }

    #pragma unroll
    for (int jh = 0; jh < 2; ++jh) {
        for (int k4 = 0; k4 < 64; ++k4) {
            float4 hA = *(const float4*)(Ht + r * 260 + 4 * k4);
            float4 hB = *(const float4*)(Ht + (r + 8) * 260 + 4 * k4);
            #pragma unroll
            for (int j = 0; j < 8; ++j) {
                int jj = jh * 8 + j;
                int s  = cc + 32 * jj;
                float4 e = E4[(size_t)s * 64 + k4];
                accA[jj] += hA.x*e.x + hA.y*e.y + hA.z*e.z + hA.w*e.w;
                accB[jj] += hB.x*e.x + hB.y*e.y + hB.z*e.z + hB.w*e.w;
            }
        }
    }
    #pragma unroll
    for (int jj = 0; jj < 16; ++jj) {
        sc[r * 520 + cc + 32 * jj]       = accA[jj];
        sc[(r + 8) * 520 + cc + 32 * jj] = accB[jj];
    }
    __syncthreads();

    // ---- softmax per row (16 lanes per row) ----
    {
        int trr = tid >> 4;   // 0..15
        int ii  = tid & 15;
        float vals[32];
        float mx = -1e30f;
        #pragma unroll
        for (int j = 0; j < 32; ++j) {
            vals[j] = sc[trr * 520 + ii + 16 * j];
            mx = fmaxf(mx, vals[j]);
        }
        #pragma unroll
        for (int off = 1; off < 16; off <<= 1) mx = fmaxf(mx, __shfl_xor(mx, off));
        float sum = 0.f;
        #pragma unroll
        for (int j = 0; j < 32; ++j) {
            float e = __expf(vals[j] - mx);
            sum += e;
            sc[trr * 520 + ii + 16 * j] = e;
        }
        #pragma unroll
        for (int off = 1; off < 16; off <<= 1) sum += __shfl_xor(sum, off);
        if (ii == 0) rsum[trr] = sum;
    }
    __syncthreads();

    // ---- phase C: ctx[t][d] = sum_s attn[t][s] * E[s][d] ----
    {
        int tc = tid >> 4;   // t row 0..15
        int dg = tid & 15;   // d-group
        float4 a0 = {0,0,0,0}, a1 = {0,0,0,0}, a2 = {0,0,0,0}, a3 = {0,0,0,0};
        const float* scr = sc + tc * 520;
        for (int sq = 0; sq < 128; ++sq) {
            float4 w4 = *(const float4*)(scr + 4 * sq);
            #pragma unroll
            for (int u = 0; u < 4; ++u) {
                int s = 4 * sq + u;
                float w = (u == 0) ? w4.x : (u == 1) ? w4.y : (u == 2) ? w4.z : w4.w;
                const float4* ep = E4 + (size_t)s * 64;
                float4 e0v = ep[dg];
                float4 e1v = ep[dg + 16];
                float4 e2v = ep[dg + 32];
                float4 e3v = ep[dg + 48];
                a0.x += w*e0v.x; a0.y += w*e0v.y; a0.z += w*e0v.z; a0.w += w*e0v.w;
                a1.x += w*e1v.x; a1.y += w*e1v.y; a1.z += w*e1v.z; a1.w += w*e1v.w;
                a2.x += w*e2v.x; a2.y += w*e2v.y; a2.z += w*e2v.z; a2.w += w*e2v.w;
                a3.x += w*e3v.x; a3.y += w*e3v.y; a3.z += w*e3v.z; a3.w += w*e3v.w;
            }
        }
        float scl = 1.0f / rsum[tc];
        float4* op = (float4*)(out + ((size_t)b * T_ + t0 + tc) * 512 + 256);
        a0.x *= scl; a0.y *= scl; a0.z *= scl; a0.w *= scl;
        a1.x *= scl; a1.y *= scl; a1.z *= scl; a1.w *= scl;
        a2.x *= scl; a2.y *= scl; a2.z *= scl; a2.w *= scl;
        a3.x *= scl; a3.y *= scl; a3.z *= scl; a3.w *= scl;
        op[dg]      = a0;
        op[dg + 16] = a1;
        op[dg + 32] = a2;
        op[dg + 48] = a3;
    }
}

// -------------------- launch --------------------

extern "C" void kernel_launch(void* const* d_in, const int* in_sizes, int n_in,
                              void* d_out, int out_size, void* d_ws, size_t ws_size,
                              hipStream_t stream)
{
    const float* de  = (const float*)d_in[0];
    const float* h0  = (const float*)d_in[1];
    const float* c0  = (const float*)d_in[2];
    const float* E   = (const float*)d_in[3];
    const float* Wih = (const float*)d_in[4];
    const float* Whh = (const float*)d_in[5];
    const float* bih = (const float*)d_in[6];
    const float* bhh = (const float*)d_in[7];
    float* out = (float*)d_out;
    float* ws  = (float*)d_ws;

    prep_weights<<<1028, 256, 0, stream>>>(Wih, Whh, bih, bhh, ws);
    prep_state<<<64, 256, 0, stream>>>(h0, c0, de, ws);

    float* Wc   = ws + WS_WC;
    float* bias = ws + WS_BIAS;
    float* hb0  = ws + WS_H0;
    float* hb1  = ws + WS_H1;
    float* eb   = ws + WS_E;
    float* cb   = ws + WS_C;

    for (int t = 0; t < T_; ++t) {
        float* hprev = (t & 1) ? hb1 : hb0;
        float* hnext = (t & 1) ? hb0 : hb1;
        lstm_step<<<64, 256, 0, stream>>>(Wc, bias, Wih, Whh, hprev, hnext, eb, cb, out, t);
    }

    attn_kernel<<<dim3(32, 64), 256, 0, stream>>>(E, out);
}

// Round 2
// 7576.493 us; speedup vs baseline: 1.0559x; 1.0559x over previous
//
#include <hip/hip_runtime.h>
#include <cstdint>
#include <cstddef>

#define B_  64
#define T_  512
#define S_  512
#define D_  256

#define GROUPS 16   // batch groups, 4 batches each
#define BPG    16   // blocks per group, 16 h-dims each

// ---- ws layout ----
// [0, 2048) bytes : group barrier counters (uint32, group g at u32 index g*32)
// floats from index 512: hbuf ping-pong, 2 x 16384 floats ([parity][b][d])

__global__ __launch_bounds__(256) void ws_init(uint32_t* __restrict__ ctr) {
    int i = blockIdx.x * 256 + threadIdx.x;
    if (i < 512) ctr[i] = 0;
}

__global__ __launch_bounds__(256, 1) void lstm_persistent(
    const float* __restrict__ de,  const float* __restrict__ h0,
    const float* __restrict__ c0,
    const float* __restrict__ Wih, const float* __restrict__ Whh,
    const float* __restrict__ bih, const float* __restrict__ bhh,
    float* __restrict__ out, uint32_t* __restrict__ ctr_base,
    float* __restrict__ hbuf)
{
    __shared__ float wlds[64 * 260];  // Wc rows, pad-260 (2-way max, free)
    __shared__ float hlds[4 * 260];   // group h
    __shared__ float glds[256];       // gates [gate][dl][bl]
    __shared__ float blds[64];        // bias

    const int tid = threadIdx.x;
    const int g   = blockIdx.x >> 4;   // group 0..15
    const int jb  = blockIdx.x & 15;   // d-chunk 0..15

    // compute-phase mapping: one gate-row x batch per thread
    const int row  = tid >> 2;         // 0..63 local gate row
    const int blc  = tid & 3;          // batch lane 0..3
    const int gate = row >> 4;
    const int dlc  = row & 15;
    const int grow = (gate << 8) + (jb << 4) + dlc;  // global gate row 0..1023

    // stage Wc = Wih + Whh (64 rows x 256), coalesced over k
    for (int idx = tid; idx < 64 * 256; idx += 256) {
        int r = idx >> 8, k = idx & 255;
        int gr = ((r >> 4) << 8) + (jb << 4) + (r & 15);
        wlds[r * 260 + k] = Wih[(size_t)gr * 256 + k] + Whh[(size_t)gr * 256 + k];
    }
    if (tid < 64) {
        int gr = ((tid >> 4) << 8) + (jb << 4) + (tid & 15);
        blds[tid] = bih[gr] + bhh[gr];
    }

    // combine-phase mapping: one (b, d) per thread (tid < 64)
    const int blx = tid >> 4;          // 0..3
    const int dlx = tid & 15;          // 0..15
    const int bx  = g * 4 + blx;
    const int dx  = jb * 16 + dlx;
    float c_reg = (tid < 64) ? c0[(size_t)bx * 256 + dx] : 0.f;

    uint32_t* ctr = ctr_base + g * 32;  // one 128B line per group
    __syncthreads();

    for (int t = 0; t < T_; ++t) {
        float a0 = blds[row], a1 = 0.f, a2 = 0.f, a3 = 0.f;

        if (t == 0) {
            // gates0 = Wih . e0 + Whh . h0 + bias   (weights from L2, once)
            for (int m = 0; m < 4; ++m) {
                int idx = m * 256 + tid; int bl = idx >> 8, k = idx & 255;
                hlds[bl * 260 + k] = h0[(size_t)(g * 4 + bl) * 256 + k];
            }
            __syncthreads();
            {
                const float4* w4 = (const float4*)(Whh + (size_t)grow * 256);
                const float*  hr = hlds + blc * 260;
                #pragma unroll 8
                for (int k4 = 0; k4 < 64; ++k4) {
                    float4 w = w4[k4];
                    float4 h = *(const float4*)(hr + 4 * k4);
                    a0 += w.x * h.x; a1 += w.y * h.y; a2 += w.z * h.z; a3 += w.w * h.w;
                }
            }
            __syncthreads();
            for (int m = 0; m < 4; ++m) {
                int idx = m * 256 + tid; int bl = idx >> 8, k = idx & 255;
                hlds[bl * 260 + k] = de[(size_t)(g * 4 + bl) * T_ * D_ + k];
            }
            __syncthreads();
            {
                const float4* w4 = (const float4*)(Wih + (size_t)grow * 256);
                const float*  hr = hlds + blc * 260;
                #pragma unroll 8
                for (int k4 = 0; k4 < 64; ++k4) {
                    float4 w = w4[k4];
                    float4 h = *(const float4*)(hr + 4 * k4);
                    a0 += w.x * h.x; a1 += w.y * h.y; a2 += w.z * h.z; a3 += w.w * h.w;
                }
            }
        } else {
            // stage group h from ping-pong buffer (L1 invalidated by acquire fence)
            const float* hp = hbuf + ((t + 1) & 1) * 16384 + g * 1024;
            for (int m = 0; m < 4; ++m) {
                int idx = m * 256 + tid; int bl = idx >> 8, k = idx & 255;
                hlds[bl * 260 + k] = hp[bl * 256 + k];
            }
            __syncthreads();
            const float* wr = wlds + row * 260;
            const float* hr = hlds + blc * 260;
            #pragma unroll 8
            for (int k4 = 0; k4 < 64; ++k4) {
                float4 w = *(const float4*)(wr + 4 * k4);
                float4 h = *(const float4*)(hr + 4 * k4);
                a0 += w.x * h.x; a1 += w.y * h.y; a2 += w.z * h.z; a3 += w.w * h.w;
            }
        }
        glds[gate * 64 + dlc * 4 + blc] = (a0 + a1) + (a2 + a3);
        __syncthreads();

        if (tid < 64) {
            float gi = glds[      dlx * 4 + blx];
            float gf = glds[ 64 + dlx * 4 + blx];
            float gg = glds[128 + dlx * 4 + blx];
            float go = glds[192 + dlx * 4 + blx];
            float si = 1.f / (1.f + __expf(-gi));
            float sf = 1.f / (1.f + __expf(-gf));
            float so = 1.f / (1.f + __expf(-go));
            c_reg = sf * c_reg + si * tanhf(gg);
            float hn = so * tanhf(c_reg);
            out[((size_t)bx * T_ + t) * 512 + dx] = hn;
            // write-through to coherent point so peer XCDs see it
            __hip_atomic_store(hbuf + (t & 1) * 16384 + (size_t)bx * 256 + dx, hn,
                               __ATOMIC_RELAXED, __HIP_MEMORY_SCOPE_AGENT);
        }
        if (t == T_ - 1) break;

        // per-group barrier: release -> arrive -> spin -> acquire
        __syncthreads();                       // drains each wave's vmcnt
        if (tid == 0) {
            __threadfence();                   // agent release
            atomicAdd(ctr, 1u);
            uint32_t target = (uint32_t)(BPG * (t + 1));
            while (__hip_atomic_load(ctr, __ATOMIC_RELAXED,
                                     __HIP_MEMORY_SCOPE_AGENT) < target) {
                __builtin_amdgcn_s_sleep(1);
            }
        }
        __syncthreads();
        __builtin_amdgcn_fence(__ATOMIC_ACQUIRE, "agent");  // invalidate stale L1/L2
    }
}

// -------------------- attention (unchanged from R0) --------------------

__global__ __launch_bounds__(256) void attn_kernel(
    const float* __restrict__ E, float* __restrict__ out)
{
    int tt = blockIdx.x;
    int b  = blockIdx.y;
    int t0 = tt * 16;
    int tid = threadIdx.x;

    __shared__ float Ht[16 * 260];
    __shared__ float sc[16 * 520];
    __shared__ float rsum[16];

    #pragma unroll
    for (int m = 0; m < 4; ++m) {
        int f = m * 256 + tid;
        int t = f >> 6, j = f & 63;
        float4 v = *(const float4*)(out + ((size_t)b * T_ + t0 + t) * 512 + 4 * j);
        *(float4*)(Ht + t * 260 + 4 * j) = v;
    }
    __syncthreads();

    const float4* E4 = (const float4*)E + (size_t)b * S_ * 64;

    int r  = tid >> 5;
    int cc = tid & 31;
    float accA[16], accB[16];
    #pragma unroll
    for (int jj = 0; jj < 16; ++jj) { accA[jj] = 0.f; accB[jj] = 0.f; }

    #pragma unroll
    for (int jh = 0; jh < 2; ++jh) {
        for (int k4 = 0; k4 < 64; ++k4) {
            float4 hA = *(const float4*)(Ht + r * 260 + 4 * k4);
            float4 hB = *(const float4*)(Ht + (r + 8) * 260 + 4 * k4);
            #pragma unroll
            for (int j = 0; j < 8; ++j) {
                int jj = jh * 8 + j;
                int s  = cc + 32 * jj;
                float4 e = E4[(size_t)s * 64 + k4];
                accA[jj] += hA.x*e.x + hA.y*e.y + hA.z*e.z + hA.w*e.w;
                accB[jj] += hB.x*e.x + hB.y*e.y + hB.z*e.z + hB.w*e.w;
            }
        }
    }
    #pragma unroll
    for (int jj = 0; jj < 16; ++jj) {
        sc[r * 520 + cc + 32 * jj]       = accA[jj];
        sc[(r + 8) * 520 + cc + 32 * jj] = accB[jj];
    }
    __syncthreads();

    {
        int trr = tid >> 4;
        int ii  = tid & 15;
        float vals[32];
        float mx = -1e30f;
        #pragma unroll
        for (int j = 0; j < 32; ++j) {
            vals[j] = sc[trr * 520 + ii + 16 * j];
            mx = fmaxf(mx, vals[j]);
        }
        #pragma unroll
        for (int off = 1; off < 16; off <<= 1) mx = fmaxf(mx, __shfl_xor(mx, off));
        float sum = 0.f;
        #pragma unroll
        for (int j = 0; j < 32; ++j) {
            float e = __expf(vals[j] - mx);
            sum += e;
            sc[trr * 520 + ii + 16 * j] = e;
        }
        #pragma unroll
        for (int off = 1; off < 16; off <<= 1) sum += __shfl_xor(sum, off);
        if (ii == 0) rsum[trr] = sum;
    }
    __syncthreads();

    {
        int tc = tid >> 4;
        int dg = tid & 15;
        float4 a0 = {0,0,0,0}, a1 = {0,0,0,0}, a2 = {0,0,0,0}, a3 = {0,0,0,0};
        const float* scr = sc + tc * 520;
        for (int sq = 0; sq < 128; ++sq) {
            float4 w4 = *(const float4*)(scr + 4 * sq);
            #pragma unroll
            for (int u = 0; u < 4; ++u) {
                int s = 4 * sq + u;
                float w = (u == 0) ? w4.x : (u == 1) ? w4.y : (u == 2) ? w4.z : w4.w;
                const float4* ep = E4 + (size_t)s * 64;
                float4 e0v = ep[dg];
                float4 e1v = ep[dg + 16];
                float4 e2v = ep[dg + 32];
                float4 e3v = ep[dg + 48];
                a0.x += w*e0v.x; a0.y += w*e0v.y; a0.z += w*e0v.z; a0.w += w*e0v.w;
                a1.x += w*e1v.x; a1.y += w*e1v.y; a1.z += w*e1v.z; a1.w += w*e1v.w;
                a2.x += w*e2v.x; a2.y += w*e2v.y; a2.z += w*e2v.z; a2.w += w*e2v.w;
                a3.x += w*e3v.x; a3.y += w*e3v.y; a3.z += w*e3v.z; a3.w += w*e3v.w;
            }
        }
        float scl = 1.0f / rsum[tc];
        float4* op = (float4*)(out + ((size_t)b * T_ + t0 + tc) * 512 + 256);
        a0.x *= scl; a0.y *= scl; a0.z *= scl; a0.w *= scl;
        a1.x *= scl; a1.y *= scl; a1.z *= scl; a1.w *= scl;
        a2.x *= scl; a2.y *= scl; a2.z *= scl; a2.w *= scl;
        a3.x *= scl; a3.y *= scl; a3.z *= scl; a3.w *= scl;
        op[dg]      = a0;
        op[dg + 16] = a1;
        op[dg + 32] = a2;
        op[dg + 48] = a3;
    }
}

// -------------------- launch --------------------

extern "C" void kernel_launch(void* const* d_in, const int* in_sizes, int n_in,
                              void* d_out, int out_size, void* d_ws, size_t ws_size,
                              hipStream_t stream)
{
    const float* de  = (const float*)d_in[0];
    const float* h0  = (const float*)d_in[1];
    const float* c0  = (const float*)d_in[2];
    const float* E   = (const float*)d_in[3];
    const float* Wih = (const float*)d_in[4];
    const float* Whh = (const float*)d_in[5];
    const float* bih = (const float*)d_in[6];
    const float* bhh = (const float*)d_in[7];
    float* out = (float*)d_out;

    uint32_t* ctr  = (uint32_t*)d_ws;
    float*    hbuf = (float*)d_ws + 512;

    ws_init<<<2, 256, 0, stream>>>(ctr);

    void* args[] = {(void*)&de, (void*)&h0, (void*)&c0, (void*)&Wih, (void*)&Whh,
                    (void*)&bih, (void*)&bhh, (void*)&out, (void*)&ctr, (void*)&hbuf};
    hipLaunchCooperativeKernel((const void*)lstm_persistent,
                               dim3(GROUPS * BPG), dim3(256), args, 0, stream);

    attn_kernel<<<dim3(32, 64), 256, 0, stream>>>(E, out);
}

// Round 3
// 3125.276 us; speedup vs baseline: 2.5598x; 2.4243x over previous
//
#include <hip/hip_runtime.h>
#include <cstdint>
#include <cstddef>

#define B_  64
#define T_  512
#define S_  512
#define D_  256

#define GROUPS 16   // batch groups, 4 batches each
#define BPG    16   // blocks per group, 16 h-dims each

// ---- ws layout (floats) ----
// hbuf ring: 2 slots x 16384 floats ([slot][b][d]), values stored as h + bias
// bias = 4 + 4*((t>>1)&1)  -> slot t&1; stale/other-step values differ by >=3

__global__ __launch_bounds__(256) void ws_init(float* __restrict__ hbuf) {
    int i = blockIdx.x * 256 + threadIdx.x;
    if (i < 2 * 16384)
        __hip_atomic_store(hbuf + i, 0.f, __ATOMIC_RELAXED, __HIP_MEMORY_SCOPE_AGENT);
}

__global__ __launch_bounds__(256, 1) void lstm_persistent(
    const float* __restrict__ de,  const float* __restrict__ h0,
    const float* __restrict__ c0,
    const float* __restrict__ Wih, const float* __restrict__ Whh,
    const float* __restrict__ bih, const float* __restrict__ bhh,
    float* __restrict__ out, float* __restrict__ hbuf)
{
    __shared__ float wlds[64 * 260];  // Wc rows, pad-260
    __shared__ float hlds[4 * 260];   // group h
    __shared__ float glds[256];       // gates [gate][dl][bl]
    __shared__ float blds[64];        // bias

    const int tid = threadIdx.x;
    const int g   = blockIdx.x >> 4;   // group 0..15
    const int jb  = blockIdx.x & 15;   // d-chunk 0..15

    const int row  = tid >> 2;         // 0..63 local gate row
    const int blc  = tid & 3;          // batch lane 0..3
    const int gate = row >> 4;
    const int dlc  = row & 15;
    const int grow = (gate << 8) + (jb << 4) + dlc;

    // stage Wc = Wih + Whh (64 rows x 256)
    for (int idx = tid; idx < 64 * 256; idx += 256) {
        int r = idx >> 8, k = idx & 255;
        int gr = ((r >> 4) << 8) + (jb << 4) + (r & 15);
        wlds[r * 260 + k] = Wih[(size_t)gr * 256 + k] + Whh[(size_t)gr * 256 + k];
    }
    if (tid < 64) {
        int gr = ((tid >> 4) << 8) + (jb << 4) + (tid & 15);
        blds[tid] = bih[gr] + bhh[gr];
    }

    const int blx = tid >> 4;          // 0..3
    const int dlx = tid & 15;          // 0..15
    const int bx  = g * 4 + blx;
    const int dx  = jb * 16 + dlx;
    float c_reg = (tid < 64) ? c0[(size_t)bx * 256 + dx] : 0.f;

    // per-thread consumer indices (4 elements of the group's 1024-float h tile)
    const int i0 = tid, i1 = 256 + tid, i2 = 512 + tid, i3 = 768 + tid;

    __syncthreads();

    for (int t = 0; t < T_; ++t) {
        float a0 = blds[row], a1 = 0.f, a2 = 0.f, a3 = 0.f;

        if (t == 0) {
            for (int m = 0; m < 4; ++m) {
                int idx = m * 256 + tid; int bl = idx >> 8, k = idx & 255;
                hlds[bl * 260 + k] = h0[(size_t)(g * 4 + bl) * 256 + k];
            }
            __syncthreads();
            {
                const float4* w4 = (const float4*)(Whh + (size_t)grow * 256);
                const float*  hr = hlds + blc * 260;
                #pragma unroll 8
                for (int k4 = 0; k4 < 64; ++k4) {
                    float4 w = w4[k4];
                    float4 h = *(const float4*)(hr + 4 * k4);
                    a0 += w.x * h.x; a1 += w.y * h.y; a2 += w.z * h.z; a3 += w.w * h.w;
                }
            }
            __syncthreads();
            for (int m = 0; m < 4; ++m) {
                int idx = m * 256 + tid; int bl = idx >> 8, k = idx & 255;
                hlds[bl * 260 + k] = de[(size_t)(g * 4 + bl) * T_ * D_ + k];
            }
            __syncthreads();
            {
                const float4* w4 = (const float4*)(Wih + (size_t)grow * 256);
                const float*  hr = hlds + blc * 260;
                #pragma unroll 8
                for (int k4 = 0; k4 < 64; ++k4) {
                    float4 w = w4[k4];
                    float4 h = *(const float4*)(hr + 4 * k4);
                    a0 += w.x * h.x; a1 += w.y * h.y; a2 += w.z * h.z; a3 += w.w * h.w;
                }
            }
        } else {
            // dataflow: spin on h_{t-1} values directly (payload IS the flag)
            const float bias = 4.0f + 4.0f * (float)(((t - 1) >> 1) & 1);
            const float* hp = hbuf + ((t - 1) & 1) * 16384 + g * 1024;
            float v0 = __hip_atomic_load(hp + i0, __ATOMIC_RELAXED, __HIP_MEMORY_SCOPE_AGENT);
            float v1 = __hip_atomic_load(hp + i1, __ATOMIC_RELAXED, __HIP_MEMORY_SCOPE_AGENT);
            float v2 = __hip_atomic_load(hp + i2, __ATOMIC_RELAXED, __HIP_MEMORY_SCOPE_AGENT);
            float v3 = __hip_atomic_load(hp + i3, __ATOMIC_RELAXED, __HIP_MEMORY_SCOPE_AGENT);
            while (!(__builtin_fabsf(v0 - bias) < 1.5f))
                v0 = __hip_atomic_load(hp + i0, __ATOMIC_RELAXED, __HIP_MEMORY_SCOPE_AGENT);
            while (!(__builtin_fabsf(v1 - bias) < 1.5f))
                v1 = __hip_atomic_load(hp + i1, __ATOMIC_RELAXED, __HIP_MEMORY_SCOPE_AGENT);
            while (!(__builtin_fabsf(v2 - bias) < 1.5f))
                v2 = __hip_atomic_load(hp + i2, __ATOMIC_RELAXED, __HIP_MEMORY_SCOPE_AGENT);
            while (!(__builtin_fabsf(v3 - bias) < 1.5f))
                v3 = __hip_atomic_load(hp + i3, __ATOMIC_RELAXED, __HIP_MEMORY_SCOPE_AGENT);
            hlds[(i0 >> 8) * 260 + (i0 & 255)] = v0 - bias;
            hlds[(i1 >> 8) * 260 + (i1 & 255)] = v1 - bias;
            hlds[(i2 >> 8) * 260 + (i2 & 255)] = v2 - bias;
            hlds[(i3 >> 8) * 260 + (i3 & 255)] = v3 - bias;
            __syncthreads();
            const float* wr = wlds + row * 260;
            const float* hr = hlds + blc * 260;
            #pragma unroll 8
            for (int k4 = 0; k4 < 64; ++k4) {
                float4 w = *(const float4*)(wr + 4 * k4);
                float4 h = *(const float4*)(hr + 4 * k4);
                a0 += w.x * h.x; a1 += w.y * h.y; a2 += w.z * h.z; a3 += w.w * h.w;
            }
        }
        glds[gate * 64 + dlc * 4 + blc] = (a0 + a1) + (a2 + a3);
        __syncthreads();

        if (tid < 64) {
            float gi = glds[      dlx * 4 + blx];
            float gf = glds[ 64 + dlx * 4 + blx];
            float gg = glds[128 + dlx * 4 + blx];
            float go = glds[192 + dlx * 4 + blx];
            float si = 1.f / (1.f + __expf(-gi));
            float sf = 1.f / (1.f + __expf(-gf));
            float so = 1.f / (1.f + __expf(-go));
            float tg = 1.f - 2.f / (1.f + __expf(2.f * gg));
            c_reg = sf * c_reg + si * tg;
            float tc = 1.f - 2.f / (1.f + __expf(2.f * c_reg));
            float hn = so * tc;
            if (t < T_ - 1) {
                float wbias = 4.0f + 4.0f * (float)((t >> 1) & 1);
                __hip_atomic_store(hbuf + (t & 1) * 16384 + (size_t)bx * 256 + dx,
                                   hn + wbias, __ATOMIC_RELAXED, __HIP_MEMORY_SCOPE_AGENT);
            }
            out[((size_t)bx * T_ + t) * 512 + dx] = hn;
        }
    }
}

// -------------------- attention (unchanged) --------------------

__global__ __launch_bounds__(256) void attn_kernel(
    const float* __restrict__ E, float* __restrict__ out)
{
    int tt = blockIdx.x;
    int b  = blockIdx.y;
    int t0 = tt * 16;
    int tid = threadIdx.x;

    __shared__ float Ht[16 * 260];
    __shared__ float sc[16 * 520];
    __shared__ float rsum[16];

    #pragma unroll
    for (int m = 0; m < 4; ++m) {
        int f = m * 256 + tid;
        int t = f >> 6, j = f & 63;
        float4 v = *(const float4*)(out + ((size_t)b * T_ + t0 + t) * 512 + 4 * j);
        *(float4*)(Ht + t * 260 + 4 * j) = v;
    }
    __syncthreads();

    const float4* E4 = (const float4*)E + (size_t)b * S_ * 64;

    int r  = tid >> 5;
    int cc = tid & 31;
    float accA[16], accB[16];
    #pragma unroll
    for (int jj = 0; jj < 16; ++jj) { accA[jj] = 0.f; accB[jj] = 0.f; }

    #pragma unroll
    for (int jh = 0; jh < 2; ++jh) {
        for (int k4 = 0; k4 < 64; ++k4) {
            float4 hA = *(const float4*)(Ht + r * 260 + 4 * k4);
            float4 hB = *(const float4*)(Ht + (r + 8) * 260 + 4 * k4);
            #pragma unroll
            for (int j = 0; j < 8; ++j) {
                int jj = jh * 8 + j;
                int s  = cc + 32 * jj;
                float4 e = E4[(size_t)s * 64 + k4];
                accA[jj] += hA.x*e.x + hA.y*e.y + hA.z*e.z + hA.w*e.w;
                accB[jj] += hB.x*e.x + hB.y*e.y + hB.z*e.z + hB.w*e.w;
            }
        }
    }
    #pragma unroll
    for (int jj = 0; jj < 16; ++jj) {
        sc[r * 520 + cc + 32 * jj]       = accA[jj];
        sc[(r + 8) * 520 + cc + 32 * jj] = accB[jj];
    }
    __syncthreads();

    {
        int trr = tid >> 4;
        int ii  = tid & 15;
        float vals[32];
        float mx = -1e30f;
        #pragma unroll
        for (int j = 0; j < 32; ++j) {
            vals[j] = sc[trr * 520 + ii + 16 * j];
            mx = fmaxf(mx, vals[j]);
        }
        #pragma unroll
        for (int off = 1; off < 16; off <<= 1) mx = fmaxf(mx, __shfl_xor(mx, off));
        float sum = 0.f;
        #pragma unroll
        for (int j = 0; j < 32; ++j) {
            float e = __expf(vals[j] - mx);
            sum += e;
            sc[trr * 520 + ii + 16 * j] = e;
        }
        #pragma unroll
        for (int off = 1; off < 16; off <<= 1) sum += __shfl_xor(sum, off);
        if (ii == 0) rsum[trr] = sum;
    }
    __syncthreads();

    {
        int tc = tid >> 4;
        int dg = tid & 15;
        float4 a0 = {0,0,0,0}, a1 = {0,0,0,0}, a2 = {0,0,0,0}, a3 = {0,0,0,0};
        const float* scr = sc + tc * 520;
        for (int sq = 0; sq < 128; ++sq) {
            float4 w4 = *(const float4*)(scr + 4 * sq);
            #pragma unroll
            for (int u = 0; u < 4; ++u) {
                int s = 4 * sq + u;
                float w = (u == 0) ? w4.x : (u == 1) ? w4.y : (u == 2) ? w4.z : w4.w;
                const float4* ep = E4 + (size_t)s * 64;
                float4 e0v = ep[dg];
                float4 e1v = ep[dg + 16];
                float4 e2v = ep[dg + 32];
                float4 e3v = ep[dg + 48];
                a0.x += w*e0v.x; a0.y += w*e0v.y; a0.z += w*e0v.z; a0.w += w*e0v.w;
                a1.x += w*e1v.x; a1.y += w*e1v.y; a1.z += w*e1v.z; a1.w += w*e1v.w;
                a2.x += w*e2v.x; a2.y += w*e2v.y; a2.z += w*e2v.z; a2.w += w*e2v.w;
                a3.x += w*e3v.x; a3.y += w*e3v.y; a3.z += w*e3v.z; a3.w += w*e3v.w;
            }
        }
        float scl = 1.0f / rsum[tc];
        float4* op = (float4*)(out + ((size_t)b * T_ + t0 + tc) * 512 + 256);
        a0.x *= scl; a0.y *= scl; a0.z *= scl; a0.w *= scl;
        a1.x *= scl; a1.y *= scl; a1.z *= scl; a1.w *= scl;
        a2.x *= scl; a2.y *= scl; a2.z *= scl; a2.w *= scl;
        a3.x *= scl; a3.y *= scl; a3.z *= scl; a3.w *= scl;
        op[dg]      = a0;
        op[dg + 16] = a1;
        op[dg + 32] = a2;
        op[dg + 48] = a3;
    }
}

// -------------------- launch --------------------

extern "C" void kernel_launch(void* const* d_in, const int* in_sizes, int n_in,
                              void* d_out, int out_size, void* d_ws, size_t ws_size,
                              hipStream_t stream)
{
    const float* de  = (const float*)d_in[0];
    const float* h0  = (const float*)d_in[1];
    const float* c0  = (const float*)d_in[2];
    const float* E   = (const float*)d_in[3];
    const float* Wih = (const float*)d_in[4];
    const float* Whh = (const float*)d_in[5];
    const float* bih = (const float*)d_in[6];
    const float* bhh = (const float*)d_in[7];
    float* out  = (float*)d_out;
    float* hbuf = (float*)d_ws;

    ws_init<<<128, 256, 0, stream>>>(hbuf);

    void* args[] = {(void*)&de, (void*)&h0, (void*)&c0, (void*)&Wih, (void*)&Whh,
                    (void*)&bih, (void*)&bhh, (void*)&out, (void*)&hbuf};
    hipLaunchCooperativeKernel((const void*)lstm_persistent,
                               dim3(GROUPS * BPG), dim3(256), args, 0, stream);

    attn_kernel<<<dim3(32, 64), 256, 0, stream>>>(E, out);
}

// Round 4
// 2563.243 us; speedup vs baseline: 3.1211x; 1.2193x over previous
//
#include <hip/hip_runtime.h>
#include <cstdint>
#include <cstddef>

#define B_  64
#define T_  512
#define S_  512
#define D_  256

#define GROUPS 16   // batch groups, 4 batches each
#define BPG    16   // blocks per group, 16 h-dims each

// ---- ws layout (floats) ----
// hbuf ring: 2 slots x 16384 floats ([slot][b][d]), stored as h + bias
// bias = 4 + 4*((t>>1)&1); detection window +-1.5 (|h|<1)

__global__ __launch_bounds__(256) void ws_init(float* __restrict__ hbuf) {
    int i = blockIdx.x * 256 + threadIdx.x;
    if (i < 2 * 16384) hbuf[i] = 0.f;
}

// cache-bypassing (coherent) 16B load / 4B store
__device__ __forceinline__ float4 ldx4_cg(const float* p) {
    float4 r;
    asm volatile("global_load_dwordx4 %0, %1, off sc0 sc1\n\ts_waitcnt vmcnt(0)"
                 : "=v"(r) : "v"(p) : "memory");
    return r;
}
__device__ __forceinline__ void st_cg(float* p, float v) {
    asm volatile("global_store_dword %0, %1, off sc0 sc1" :: "v"(p), "v"(v) : "memory");
}
__device__ __forceinline__ bool rdy4(float4 v, float rb) {
    return __builtin_fabsf(v.x - rb) < 1.5f && __builtin_fabsf(v.y - rb) < 1.5f &&
           __builtin_fabsf(v.z - rb) < 1.5f && __builtin_fabsf(v.w - rb) < 1.5f;
}

__global__ __launch_bounds__(256, 1) void lstm_persistent(
    const float* __restrict__ de,  const float* __restrict__ h0,
    const float* __restrict__ c0,
    const float* __restrict__ Wih, const float* __restrict__ Whh,
    const float* __restrict__ bih, const float* __restrict__ bhh,
    float* __restrict__ out, float* __restrict__ hbuf)
{
    __shared__ float wlds[64 * 260];  // Wc rows (gate*16+dlc), pad-260
    __shared__ float hlds[4 * 260];   // group h [bl][k]
    __shared__ float blds[64];        // bias rows

    const int tid = threadIdx.x;
    const int grp = blockIdx.x >> 4;   // 0..15
    const int jb  = blockIdx.x & 15;   // d-chunk

    // thread = (output, k-quarter): out_id = (blc*16+dlc), ks = k-interleave lane
    const int out_id = tid >> 2;       // 0..63
    const int ks     = tid & 3;        // 0..3
    const int blc    = out_id >> 4;    // batch 0..3
    const int dlc    = out_id & 15;    // dim 0..15

    // stage Wc = Wih + Whh (64 rows x 256) and bias
    for (int idx = tid; idx < 64 * 256; idx += 256) {
        int r = idx >> 8, k = idx & 255;
        int gr = ((r >> 4) << 8) + (jb << 4) + (r & 15);
        wlds[r * 260 + k] = Wih[(size_t)gr * 256 + k] + Whh[(size_t)gr * 256 + k];
    }
    if (tid < 64) {
        int gr = ((tid >> 4) << 8) + (jb << 4) + (tid & 15);
        blds[tid] = bih[gr] + bhh[gr];
    }

    const int bx = grp * 4 + blc;
    const int dx = jb * 16 + dlc;
    float c_reg = (ks == 0) ? c0[(size_t)bx * 256 + dx] : 0.f;

    __syncthreads();

    float acc0, acc1, acc2, acc3;
    const float* hb = hlds + blc * 260 + 4 * ks;

    #define DOT4ROWS(r0p, r1p, r2p, r3p)                                        \
        _Pragma("unroll 8")                                                     \
        for (int kk = 0; kk < 16; ++kk) {                                       \
            float4 h = *(const float4*)(hb + 16 * kk);                          \
            float4 w;                                                           \
            w = *(const float4*)((r0p) + 16 * kk);                              \
            acc0 += w.x*h.x + w.y*h.y + w.z*h.z + w.w*h.w;                      \
            w = *(const float4*)((r1p) + 16 * kk);                              \
            acc1 += w.x*h.x + w.y*h.y + w.z*h.z + w.w*h.w;                      \
            w = *(const float4*)((r2p) + 16 * kk);                              \
            acc2 += w.x*h.x + w.y*h.y + w.z*h.z + w.w*h.w;                      \
            w = *(const float4*)((r3p) + 16 * kk);                              \
            acc3 += w.x*h.x + w.y*h.y + w.z*h.z + w.w*h.w;                      \
        }

    for (int t = 0; t < T_; ++t) {
        acc0 = acc1 = acc2 = acc3 = 0.f;

        if (t == 0) {
            // h0 pass (Whh from global), then e0 pass (Wih from global)
            {
                int bl = tid >> 6, kq = tid & 63;
                *(float4*)(hlds + bl * 260 + 4 * kq) =
                    *(const float4*)(h0 + (size_t)(grp * 4 + bl) * 256 + 4 * kq);
            }
            __syncthreads();
            {
                const float* w0 = Whh + (size_t)((0 << 8) + (jb << 4) + dlc) * 256 + 4 * ks;
                const float* w1 = Whh + (size_t)((1 << 8) + (jb << 4) + dlc) * 256 + 4 * ks;
                const float* w2 = Whh + (size_t)((2 << 8) + (jb << 4) + dlc) * 256 + 4 * ks;
                const float* w3 = Whh + (size_t)((3 << 8) + (jb << 4) + dlc) * 256 + 4 * ks;
                DOT4ROWS(w0, w1, w2, w3)
            }
            __syncthreads();
            {
                int bl = tid >> 6, kq = tid & 63;
                *(float4*)(hlds + bl * 260 + 4 * kq) =
                    *(const float4*)(de + (size_t)(grp * 4 + bl) * T_ * D_ + 4 * kq);
            }
            __syncthreads();
            {
                const float* w0 = Wih + (size_t)((0 << 8) + (jb << 4) + dlc) * 256 + 4 * ks;
                const float* w1 = Wih + (size_t)((1 << 8) + (jb << 4) + dlc) * 256 + 4 * ks;
                const float* w2 = Wih + (size_t)((2 << 8) + (jb << 4) + dlc) * 256 + 4 * ks;
                const float* w3 = Wih + (size_t)((3 << 8) + (jb << 4) + dlc) * 256 + 4 * ks;
                DOT4ROWS(w0, w1, w2, w3)
            }
        } else {
            // poll own 16B chunk of the group's h tile (value-encoded flag)
            const float rb = 4.0f + 4.0f * (float)(((t - 1) >> 1) & 1);
            const float* hp = hbuf + ((t - 1) & 1) * 16384 + grp * 1024 + tid * 4;
            float4 v = ldx4_cg(hp);
            while (!rdy4(v, rb)) v = ldx4_cg(hp);
            *(float4*)(hlds + (tid >> 6) * 260 + 4 * (tid & 63)) =
                make_float4(v.x - rb, v.y - rb, v.z - rb, v.w - rb);
            __syncthreads();
            const float* w0 = wlds + (0 * 16 + dlc) * 260 + 4 * ks;
            const float* w1 = wlds + (1 * 16 + dlc) * 260 + 4 * ks;
            const float* w2 = wlds + (2 * 16 + dlc) * 260 + 4 * ks;
            const float* w3 = wlds + (3 * 16 + dlc) * 260 + 4 * ks;
            DOT4ROWS(w0, w1, w2, w3)
        }

        // k-quarter reduction within 4-lane group
        acc0 += __shfl_xor(acc0, 1); acc0 += __shfl_xor(acc0, 2);
        acc1 += __shfl_xor(acc1, 1); acc1 += __shfl_xor(acc1, 2);
        acc2 += __shfl_xor(acc2, 1); acc2 += __shfl_xor(acc2, 2);
        acc3 += __shfl_xor(acc3, 1); acc3 += __shfl_xor(acc3, 2);

        if (ks == 0) {
            float gi = acc0 + blds[dlc];
            float gf = acc1 + blds[16 + dlc];
            float gg = acc2 + blds[32 + dlc];
            float go = acc3 + blds[48 + dlc];
            float si = 1.f / (1.f + __expf(-gi));
            float sf = 1.f / (1.f + __expf(-gf));
            float so = 1.f / (1.f + __expf(-go));
            float tg = 1.f - 2.f / (1.f + __expf(2.f * gg));
            c_reg = sf * c_reg + si * tg;
            float tc = 1.f - 2.f / (1.f + __expf(2.f * c_reg));
            float hn = so * tc;
            if (t < T_ - 1) {
                float wb = 4.0f + 4.0f * (float)((t >> 1) & 1);
                st_cg(hbuf + (t & 1) * 16384 + (size_t)bx * 256 + dx, hn + wb);
            }
            out[((size_t)bx * T_ + t) * 512 + dx] = hn;
        }
        __syncthreads();   // protect hlds before next step's stage
    }
}

// -------------------- attention: LDS-tiled 2-pass, 32 t-rows/block ----------

__global__ __launch_bounds__(256, 1) void attn_kernel(
    const float* __restrict__ E, float* __restrict__ out)
{
    __shared__ float Ht [32 * 260];
    __shared__ float sc [32 * 520];
    __shared__ float Ech[32 * 260];
    __shared__ float rsum[32];

    const int tt  = blockIdx.x;      // 0..15
    const int b   = blockIdx.y;      // 0..63
    const int t0  = tt * 32;
    const int tid = threadIdx.x;

    // stage H tile (32 x 256)
    #pragma unroll
    for (int m = 0; m < 8; ++m) {
        int f = m * 256 + tid;       // float4 id 0..2047
        int t = f >> 6, j = f & 63;
        float4 v = *(const float4*)(out + ((size_t)b * T_ + t0 + t) * 512 + 4 * j);
        *(float4*)(Ht + t * 260 + 4 * j) = v;
    }

    const float* Eb = E + (size_t)b * S_ * 256;

    // ---- pass A: scores ----
    {
        const int ti = tid >> 4;     // rows {ti, ti+16}
        const int si = tid & 15;     // chunk cols {si, si+16}
        float4 pf[8];
        #pragma unroll
        for (int m = 0; m < 8; ++m) {
            int f = m * 256 + tid; int s = f >> 6, j = f & 63;
            pf[m] = *(const float4*)(Eb + (size_t)s * 256 + 4 * j);
        }
        for (int ch = 0; ch < 16; ++ch) {
            #pragma unroll
            for (int m = 0; m < 8; ++m) {
                int f = m * 256 + tid; int s = f >> 6, j = f & 63;
                *(float4*)(Ech + s * 260 + 4 * j) = pf[m];
            }
            __syncthreads();
            if (ch < 15) {
                #pragma unroll
                for (int m = 0; m < 8; ++m) {
                    int f = m * 256 + tid; int s = f >> 6, j = f & 63;
                    pf[m] = *(const float4*)(Eb + (size_t)((ch + 1) * 32 + s) * 256 + 4 * j);
                }
            }
            float a00 = 0.f, a01 = 0.f, a10 = 0.f, a11 = 0.f;
            const float* h0p = Ht + ti * 260;
            const float* h1p = Ht + (ti + 16) * 260;
            const float* e0p = Ech + si * 260;
            const float* e1p = Ech + (si + 16) * 260;
            #pragma unroll 8
            for (int k4 = 0; k4 < 64; ++k4) {
                float4 h0v = *(const float4*)(h0p + 4 * k4);
                float4 h1v = *(const float4*)(h1p + 4 * k4);
                float4 e0v = *(const float4*)(e0p + 4 * k4);
                float4 e1v = *(const float4*)(e1p + 4 * k4);
                a00 += h0v.x*e0v.x + h0v.y*e0v.y + h0v.z*e0v.z + h0v.w*e0v.w;
                a01 += h0v.x*e1v.x + h0v.y*e1v.y + h0v.z*e1v.z + h0v.w*e1v.w;
                a10 += h1v.x*e0v.x + h1v.y*e0v.y + h1v.z*e0v.z + h1v.w*e0v.w;
                a11 += h1v.x*e1v.x + h1v.y*e1v.y + h1v.z*e1v.z + h1v.w*e1v.w;
            }
            sc[ti * 520 + ch * 32 + si]             = a00;
            sc[ti * 520 + ch * 32 + si + 16]        = a01;
            sc[(ti + 16) * 520 + ch * 32 + si]      = a10;
            sc[(ti + 16) * 520 + ch * 32 + si + 16] = a11;
            __syncthreads();
        }
    }

    // ---- softmax: 8 lanes per row ----
    {
        const int rr = tid >> 3;     // 0..31
        const int ii = tid & 7;
        float* srow = sc + rr * 520;
        float mx = -1e30f;
        #pragma unroll
        for (int m = 0; m < 16; ++m) {
            float4 v = *(const float4*)(srow + 4 * (ii + 8 * m));
            mx = fmaxf(mx, fmaxf(fmaxf(v.x, v.y), fmaxf(v.z, v.w)));
        }
        mx = fmaxf(mx, __shfl_xor(mx, 1));
        mx = fmaxf(mx, __shfl_xor(mx, 2));
        mx = fmaxf(mx, __shfl_xor(mx, 4));
        float sum = 0.f;
        #pragma unroll
        for (int m = 0; m < 16; ++m) {
            float4 v = *(const float4*)(srow + 4 * (ii + 8 * m));
            v.x = __expf(v.x - mx); v.y = __expf(v.y - mx);
            v.z = __expf(v.z - mx); v.w = __expf(v.w - mx);
            sum += (v.x + v.y) + (v.z + v.w);
            *(float4*)(srow + 4 * (ii + 8 * m)) = v;
        }
        sum += __shfl_xor(sum, 1);
        sum += __shfl_xor(sum, 2);
        sum += __shfl_xor(sum, 4);
        if (ii == 0) rsum[rr] = sum;
    }
    __syncthreads();

    // ---- pass C: ctx = P @ E ----
    {
        const int tj = tid >> 4;     // rows {tj, tj+16}
        const int dj = tid & 15;     // d cols [dj*16, dj*16+16)
        float4 c0[4], c1[4];
        #pragma unroll
        for (int u = 0; u < 4; ++u) { c0[u] = make_float4(0,0,0,0); c1[u] = make_float4(0,0,0,0); }

        float4 pf[8];
        #pragma unroll
        for (int m = 0; m < 8; ++m) {
            int f = m * 256 + tid; int s = f >> 6, j = f & 63;
            pf[m] = *(const float4*)(Eb + (size_t)s * 256 + 4 * j);
        }
        for (int ch = 0; ch < 16; ++ch) {
            #pragma unroll
            for (int m = 0; m < 8; ++m) {
                int f = m * 256 + tid; int s = f >> 6, j = f & 63;
                *(float4*)(Ech + s * 260 + 4 * j) = pf[m];
            }
            __syncthreads();
            if (ch < 15) {
                #pragma unroll
                for (int m = 0; m < 8; ++m) {
                    int f = m * 256 + tid; int s = f >> 6, j = f & 63;
                    pf[m] = *(const float4*)(Eb + (size_t)((ch + 1) * 32 + s) * 256 + 4 * j);
                }
            }
            const float* p0 = sc + tj * 520 + ch * 32;
            const float* p1 = sc + (tj + 16) * 520 + ch * 32;
            #pragma unroll 4
            for (int s = 0; s < 32; ++s) {
                float w0 = p0[s], w1 = p1[s];
                const float* ep = Ech + s * 260 + dj * 16;
                #pragma unroll
                for (int u = 0; u < 4; ++u) {
                    float4 e = *(const float4*)(ep + 4 * u);
                    c0[u].x += w0*e.x; c0[u].y += w0*e.y; c0[u].z += w0*e.z; c0[u].w += w0*e.w;
                    c1[u].x += w1*e.x; c1[u].y += w1*e.y; c1[u].z += w1*e.z; c1[u].w += w1*e.w;
                }
            }
            __syncthreads();
        }
        float inv0 = 1.f / rsum[tj];
        float inv1 = 1.f / rsum[tj + 16];
        float* o0 = out + ((size_t)b * T_ + t0 + tj) * 512 + 256 + dj * 16;
        float* o1 = out + ((size_t)b * T_ + t0 + tj + 16) * 512 + 256 + dj * 16;
        #pragma unroll
        for (int u = 0; u < 4; ++u) {
            float4 r0 = make_float4(c0[u].x*inv0, c0[u].y*inv0, c0[u].z*inv0, c0[u].w*inv0);
            float4 r1 = make_float4(c1[u].x*inv1, c1[u].y*inv1, c1[u].z*inv1, c1[u].w*inv1);
            *(float4*)(o0 + 4 * u) = r0;
            *(float4*)(o1 + 4 * u) = r1;
        }
    }
}

// -------------------- launch --------------------

extern "C" void kernel_launch(void* const* d_in, const int* in_sizes, int n_in,
                              void* d_out, int out_size, void* d_ws, size_t ws_size,
                              hipStream_t stream)
{
    const float* de  = (const float*)d_in[0];
    const float* h0  = (const float*)d_in[1];
    const float* c0  = (const float*)d_in[2];
    const float* E   = (const float*)d_in[3];
    const float* Wih = (const float*)d_in[4];
    const float* Whh = (const float*)d_in[5];
    const float* bih = (const float*)d_in[6];
    const float* bhh = (const float*)d_in[7];
    float* out  = (float*)d_out;
    float* hbuf = (float*)d_ws;

    ws_init<<<128, 256, 0, stream>>>(hbuf);

    void* args[] = {(void*)&de, (void*)&h0, (void*)&c0, (void*)&Wih, (void*)&Whh,
                    (void*)&bih, (void*)&bhh, (void*)&out, (void*)&hbuf};
    hipLaunchCooperativeKernel((const void*)lstm_persistent,
                               dim3(GROUPS * BPG), dim3(256), args, 0, stream);

    attn_kernel<<<dim3(16, 64), 256, 0, stream>>>(E, out);
}